// Round 3
// baseline (7628.694 us; speedup 1.0000x reference)
//
#include <hip/hip_runtime.h>

#define NB 128
#define NT 80
#define NI 4096
#define NH 256
#define G4 1024
#define NV 6000
#define NVP 6016
#define NDEC 40

typedef unsigned short ushort_t;
typedef __attribute__((ext_vector_type(8))) short bf16x8;
typedef __attribute__((ext_vector_type(4))) float f32x4;

__device__ __forceinline__ unsigned short f2bf(float f) {
  unsigned int x = __float_as_uint(f);
  x += 0x7FFFu + ((x >> 16) & 1u);
  return (unsigned short)(x >> 16);
}
__device__ __forceinline__ ushort4 pack4(float4 v) {
  return make_ushort4(f2bf(v.x), f2bf(v.y), f2bf(v.z), f2bf(v.w));
}

// ---------------- cast kernels ----------------

// x (B,T,I) f32 -> x_bf (T,B,I) bf16
__global__ __launch_bounds__(256) void k_cast_x(const float* __restrict__ x,
                                                ushort_t* __restrict__ xb) {
  const int t = blockIdx.x, b = blockIdx.y;
  const float* src = x + ((size_t)b * NT + t) * NI;
  ushort_t* dst = xb + ((size_t)t * NB + b) * NI;
#pragma unroll
  for (int s = 0; s < 4; ++s) {
    int j = s * 1024 + threadIdx.x * 4;
    float4 v = *(const float4*)(src + j);
    *(ushort4*)(dst + j) = pack4(v);
  }
}

// flat f32 -> bf16 with zero pad to ndst (sizes % 4 == 0)
__global__ __launch_bounds__(256) void k_cast_pad(const float* __restrict__ s,
                                                  ushort_t* __restrict__ d,
                                                  int nsrc, int ndst) {
  int i = (blockIdx.x * 256 + threadIdx.x) * 4;
  if (i >= ndst) return;
  ushort4 o;
  if (i < nsrc) {
    float4 v = *(const float4*)(s + i);
    o = pack4(v);
  } else {
    o = make_ushort4(0, 0, 0, 0);
  }
  *(ushort4*)(d + i) = o;
}

// Wsum = Wih2 + Whh2 (fp32), n = 1024*256
__global__ __launch_bounds__(256) void k_addw(const float* __restrict__ a,
                                              const float* __restrict__ b,
                                              float* __restrict__ o) {
  int i = (blockIdx.x * 256 + threadIdx.x) * 4;
  float4 va = *(const float4*)(a + i);
  float4 vb = *(const float4*)(b + i);
  va.x += vb.x; va.y += vb.y; va.z += vb.z; va.w += vb.w;
  *(float4*)(o + i) = va;
}

// ---------------- bf16 MFMA GEMM: C = A @ B^T + bias_a + bias_b ----------------
// A: M x K bf16 row-major (M multiple of 128), B: Npad x K bf16 row-major
// (Npad = gridTiles*128, zero-padded rows), C: M x ldc fp32. K multiple of 32.

#define GLDS(gp, lp)                                                     \
  __builtin_amdgcn_global_load_lds(                                      \
      (const __attribute__((address_space(1))) unsigned int*)(gp),       \
      (__attribute__((address_space(3))) unsigned int*)(lp), 16, 0, 0)

__global__ __launch_bounds__(256) void k_gemm(
    const ushort_t* __restrict__ A, const ushort_t* __restrict__ Bm,
    float* __restrict__ C, const float* __restrict__ ba,
    const float* __restrict__ bb, int Nreal, int K, int ldc, int mtiles) {
  __shared__ __align__(16) ushort_t Als[128 * 32];
  __shared__ __align__(16) ushort_t Bls[128 * 32];
  const int bid = blockIdx.x;
  const int mt = bid % mtiles, nt = bid / mtiles;
  const size_t m0 = (size_t)mt * 128, n0 = (size_t)nt * 128;
  const int tid = threadIdx.x, wave = tid >> 6, lane = tid & 63;
  const int wm = (wave & 1) * 64, wn = (wave >> 1) * 64;
  const int srow = wave * 16 + (lane >> 2), skcol = (lane & 3) * 8;
  const int fr = lane & 15, kb = (lane >> 4) * 8;

  f32x4 acc[4][4];
#pragma unroll
  for (int i = 0; i < 4; ++i)
#pragma unroll
    for (int j = 0; j < 4; ++j) acc[i][j] = (f32x4){0.f, 0.f, 0.f, 0.f};

  for (int kk = 0; kk < K; kk += 32) {
    __syncthreads();  // protect LDS vs previous iteration's reads
#pragma unroll
    for (int p = 0; p < 2; ++p) {
      GLDS(A + (m0 + p * 64 + srow) * K + kk + skcol,
           &Als[(p * 64 + wave * 16) * 32]);
      GLDS(Bm + (n0 + p * 64 + srow) * K + kk + skcol,
           &Bls[(p * 64 + wave * 16) * 32]);
    }
    __syncthreads();  // drains vmcnt (global_load_lds) + lgkm
    bf16x8 af[4], bfr[4];
#pragma unroll
    for (int i = 0; i < 4; ++i)
      af[i] = *(const bf16x8*)&Als[(wm + i * 16 + fr) * 32 + kb];
#pragma unroll
    for (int j = 0; j < 4; ++j)
      bfr[j] = *(const bf16x8*)&Bls[(wn + j * 16 + fr) * 32 + kb];
#pragma unroll
    for (int i = 0; i < 4; ++i)
#pragma unroll
      for (int j = 0; j < 4; ++j)
        acc[i][j] = __builtin_amdgcn_mfma_f32_16x16x32_bf16(af[i], bfr[j],
                                                            acc[i][j], 0, 0, 0);
  }
  const int cr4 = (lane >> 4) * 4, ccn = lane & 15;
#pragma unroll
  for (int j = 0; j < 4; ++j) {
    int n = (int)n0 + wn + j * 16 + ccn;
    if (n < Nreal) {
      float bv = (ba ? ba[n] : 0.f) + (bb ? bb[n] : 0.f);
#pragma unroll
      for (int i = 0; i < 4; ++i) {
#pragma unroll
        for (int r = 0; r < 4; ++r) {
          size_t m = m0 + wm + i * 16 + cr4 + r;
          C[m * (size_t)ldc + n] = acc[i][j][r] + bv;
        }
      }
    }
  }
}

// ---------------- one LSTM step (fp32 VALU) ----------------
// gates = (inp ? inp[b,:] : (ba+bb)) + h_in @ W^T ; elementwise; write h_out, c.
// W: (1024, 256) fp32 row-major. grid = 128 blocks (8 batch-groups x 16 col-groups).
__global__ __launch_bounds__(256) void k_step(
    const float* __restrict__ inp, const float* __restrict__ ba,
    const float* __restrict__ bb, const float* __restrict__ W,
    const float* __restrict__ hin, float* __restrict__ hout,
    float* __restrict__ cst, ushort_t* __restrict__ traj, int tstride) {
  __shared__ __align__(16) float hs[16][260];
  const int bg = blockIdx.x & 7, hg = blockIdx.x >> 3;
  const int tid = threadIdx.x;
#pragma unroll
  for (int s = 0; s < 4; ++s) {
    int slot = s * 256 + tid;
    int r = slot >> 6, k4 = (slot & 63) * 4;
    *(float4*)&hs[r][k4] = *(const float4*)(hin + (size_t)(bg * 16 + r) * NH + k4);
  }
  __syncthreads();
  const int cc = tid & 15, r = tid >> 4;
  const int b = bg * 16 + r, col = hg * 16 + cc;
  float a0, a1, a2, a3;
  if (inp) {
    const float* ip = inp + (size_t)b * G4 + col;
    a0 = ip[0]; a1 = ip[256]; a2 = ip[512]; a3 = ip[768];
  } else {
    a0 = ba[col] + bb[col];
    a1 = ba[256 + col] + bb[256 + col];
    a2 = ba[512 + col] + bb[512 + col];
    a3 = ba[768 + col] + bb[768 + col];
  }
  const float* w0 = W + (size_t)(col)*NH;
  const float* w1 = W + (size_t)(256 + col) * NH;
  const float* w2 = W + (size_t)(512 + col) * NH;
  const float* w3 = W + (size_t)(768 + col) * NH;
#pragma unroll 4
  for (int k = 0; k < 256; k += 4) {
    float4 hv = *(const float4*)&hs[r][k];
    float4 q0 = *(const float4*)(w0 + k);
    float4 q1 = *(const float4*)(w1 + k);
    float4 q2 = *(const float4*)(w2 + k);
    float4 q3 = *(const float4*)(w3 + k);
    a0 = fmaf(hv.x, q0.x, a0); a0 = fmaf(hv.y, q0.y, a0);
    a0 = fmaf(hv.z, q0.z, a0); a0 = fmaf(hv.w, q0.w, a0);
    a1 = fmaf(hv.x, q1.x, a1); a1 = fmaf(hv.y, q1.y, a1);
    a1 = fmaf(hv.z, q1.z, a1); a1 = fmaf(hv.w, q1.w, a1);
    a2 = fmaf(hv.x, q2.x, a2); a2 = fmaf(hv.y, q2.y, a2);
    a2 = fmaf(hv.z, q2.z, a2); a2 = fmaf(hv.w, q2.w, a2);
    a3 = fmaf(hv.x, q3.x, a3); a3 = fmaf(hv.y, q3.y, a3);
    a3 = fmaf(hv.z, q3.z, a3); a3 = fmaf(hv.w, q3.w, a3);
  }
  float ig = 1.f / (1.f + __expf(-a0));
  float fg = 1.f / (1.f + __expf(-a1));
  float gg = tanhf(a2);
  float og = 1.f / (1.f + __expf(-a3));
  size_t idx = (size_t)b * NH + col;
  float cn = fg * cst[idx] + ig * gg;
  float hn = og * tanhf(cn);
  cst[idx] = cn;
  hout[idx] = hn;
  if (traj) traj[(size_t)b * tstride + col] = f2bf(hn);
}

// ---------------- host ----------------

extern "C" void kernel_launch(void* const* d_in, const int* in_sizes, int n_in,
                              void* d_out, int out_size, void* d_ws,
                              size_t ws_size, hipStream_t stream) {
  const float* x = (const float*)d_in[0];
  const float* Wih1 = (const float*)d_in[1];
  const float* Whh1 = (const float*)d_in[2];
  const float* bih1 = (const float*)d_in[3];
  const float* bhh1 = (const float*)d_in[4];
  const float* Wih2 = (const float*)d_in[5];
  const float* Whh2 = (const float*)d_in[6];
  const float* bih2 = (const float*)d_in[7];
  const float* bhh2 = (const float*)d_in[8];
  const float* Wout = (const float*)d_in[9];
  const float* bout = (const float*)d_in[10];
  char* ws = (char*)d_ws;

  // ws layout (bytes, all 256-aligned)
  ushort_t* x_bf   = (ushort_t*)(ws + 0);           //  83,886,080  (T,B,I) bf16
  float*    Gbuf   = (float*)(ws + 83886080);       //  41,943,040  gates input terms
  ushort_t* Wih1b  = (ushort_t*)(ws + 125829120);   //   8,388,608
  ushort_t* Wih2b  = (ushort_t*)(ws + 134217728);   //     524,288
  ushort_t* Woutb  = (ushort_t*)(ws + 134742016);   //   3,080,192  (6016x256, padded)
  float*    Wsum   = (float*)(ws + 137822208);      //   1,048,576  Wih2+Whh2 fp32
  ushort_t* ys1    = (ushort_t*)(ws + 138870784);   //   5,242,880  (80,128,256) bf16
  ushort_t* H1dec  = (ushort_t*)(ws + 144113664);   //   2,686,976  (41,128,256) bf16
  ushort_t* feats  = (ushort_t*)(ws + 146800640);   //   2,621,440  (128,40,256) bf16
  float*    states = (float*)(ws + 149422080);      //     786,432
  float* h1a = states;                // zeroed
  float* c1  = states + 32768;        // zeroed
  float* h2a = states + 65536;        // zeroed
  float* c2  = states + 98304;        // zeroed
  float* h1b = states + 131072;
  float* h2b = states + 163840;
  float* h1buf[2] = {h1a, h1b};
  float* h2buf[2] = {h2a, h2b};

  // casts + weight prep
  k_cast_x<<<dim3(NT, NB), 256, 0, stream>>>(x, x_bf);
  k_cast_pad<<<4096, 256, 0, stream>>>(Wih1, Wih1b, G4 * NI, G4 * NI);
  k_cast_pad<<<256, 256, 0, stream>>>(Wih2, Wih2b, G4 * NH, G4 * NH);
  k_cast_pad<<<1504, 256, 0, stream>>>(Wout, Woutb, NV * NH, NVP * NH);
  k_addw<<<256, 256, 0, stream>>>(Wih2, Whh2, Wsum);
  hipMemsetAsync(states, 0, 4 * 131072, stream);

  // G1 = x_bf @ Wih1^T + b1 : (10240, 1024), K=4096
  k_gemm<<<640, 256, 0, stream>>>(x_bf, Wih1b, Gbuf, bih1, bhh1, G4, NI, G4, 80);

  // encoder lstm1: 80 steps, store ys1 (bf16)
  int p1 = 0, p2 = 0;
  for (int t = 0; t < NT; ++t) {
    k_step<<<128, 256, 0, stream>>>(Gbuf + (size_t)t * NB * G4, nullptr, nullptr,
                                    Whh1, h1buf[p1], h1buf[p1 ^ 1], c1,
                                    ys1 + (size_t)t * NB * NH, NH);
    p1 ^= 1;
  }

  // G2 = ys1 @ Wih2^T + b2 (reuses Gbuf)
  k_gemm<<<640, 256, 0, stream>>>(ys1, Wih2b, Gbuf, bih2, bhh2, G4, NH, G4, 80);

  // encoder lstm2: 80 steps (only final h2,c2 needed)
  for (int t = 0; t < NT; ++t) {
    k_step<<<128, 256, 0, stream>>>(Gbuf + (size_t)t * NB * G4, nullptr, nullptr,
                                    Whh2, h2buf[p2], h2buf[p2 ^ 1], c2, nullptr, 0);
    p2 ^= 1;
  }

  // decoder lstm1: 41 zero-input pad steps, store H1dec (bf16)
  for (int s = 0; s < NDEC + 1; ++s) {
    k_step<<<128, 256, 0, stream>>>(nullptr, bih1, bhh1, Whh1, h1buf[p1],
                                    h1buf[p1 ^ 1], c1,
                                    H1dec + (size_t)s * NB * NH, NH);
    p1 ^= 1;
  }

  // G3 = H1dec[1..40] @ Wih2^T + b2 : (5120, 1024) (reuses Gbuf)
  k_gemm<<<320, 256, 0, stream>>>(H1dec + (size_t)NB * NH, Wih2b, Gbuf, bih2,
                                  bhh2, G4, NH, G4, 40);

  // decoder lstm2: 40 steps. For k>=1, y2==h2 => gates = G3[k] + h2@(Wih2+Whh2)^T + b2
  for (int k = 0; k < NDEC; ++k) {
    k_step<<<128, 256, 0, stream>>>(Gbuf + (size_t)k * NB * G4, nullptr, nullptr,
                                    (k == 0 ? Whh2 : Wsum), h2buf[p2],
                                    h2buf[p2 ^ 1], c2,
                                    feats + (size_t)k * NH, NDEC * NH);
    p2 ^= 1;
  }

  // logits = feats @ Wout^T + b_out : (5120, 6000); feats rows are b*40+k
  k_gemm<<<40 * 47, 256, 0, stream>>>(feats, Woutb, (float*)d_out, bout, nullptr,
                                      NV, NH, NV, 40);
}